// Round 1
// baseline (1020.881 us; speedup 1.0000x reference)
//
#include <hip/hip_runtime.h>

#define NQ 12
#define NL 6
#define NSTATES 4096   // 2^12
#define BATCH 8192
#define OUTF 64

// d_ws layout: rot matrices [NL*NQ][4 entries][re,im] = 576 floats

__global__ void rot_precompute(const float* __restrict__ params, float* __restrict__ rot) {
    int g = blockIdx.x * blockDim.x + threadIdx.x; // gate index l*NQ+q
    if (g >= NL * NQ) return;
    float phi = params[g * 3 + 0], theta = params[g * 3 + 1], omega = params[g * 3 + 2];
    float c = cosf(0.5f * theta), s = sinf(0.5f * theta);
    float apo = 0.5f * (phi + omega), amo = 0.5f * (phi - omega);
    float cpo = cosf(apo), spo = sinf(apo);
    float cmo = cosf(amo), smo = sinf(amo);
    float* r = rot + g * 8;
    // m00 = exp(-i*apo)*c ; m01 = -exp(i*amo)*s ; m10 = exp(-i*amo)*s ; m11 = exp(i*apo)*c
    r[0] = cpo * c;   r[1] = -spo * c;
    r[2] = -cmo * s;  r[3] = -smo * s;
    r[4] = cmo * s;   r[5] = -smo * s;
    r[6] = cpo * c;   r[7] = spo * c;
}

__global__ __launch_bounds__(256) void circuit_kernel(
    const float* __restrict__ x, const float* __restrict__ rot,
    const float* __restrict__ W, const float* __restrict__ bias,
    float* __restrict__ out)
{
    __shared__ float2 st[NSTATES];
    __shared__ float zred[4][12];
    __shared__ float zf[12];

    const int b = blockIdx.x;
    const int tid = threadIdx.x;

    // init |0...0>
    #pragma unroll
    for (int k = 0; k < 16; ++k)
        st[tid + k * 256] = make_float2(0.f, 0.f);
    if (tid == 0) st[0] = make_float2(1.f, 0.f);
    __syncthreads();

    // ---- data-encoding RY gates (per-sample angles) ----
    for (int q = 0; q < NQ; ++q) {
        float ang = 0.5f * x[b * NQ + q];
        float c = cosf(ang), s = sinf(ang);
        int bp = 11 - q;
        int lowmask = (1 << bp) - 1;
        #pragma unroll
        for (int k = 0; k < 8; ++k) {
            int p = tid + k * 256;                       // pair index 0..2047
            int i0 = ((p & ~lowmask) << 1) | (p & lowmask);
            int i1 = i0 | (1 << bp);
            float2 a0 = st[i0], a1 = st[i1];
            st[i0] = make_float2(c * a0.x - s * a1.x, c * a0.y - s * a1.y);
            st[i1] = make_float2(s * a0.x + c * a1.x, s * a0.y + c * a1.y);
        }
        __syncthreads();
    }

    // ---- variational layers ----
    for (int l = 0; l < NL; ++l) {
        // Rot gates (complex 2x2, block-uniform)
        for (int q = 0; q < NQ; ++q) {
            const float* r = rot + (l * NQ + q) * 8;
            float m00r = r[0], m00i = r[1], m01r = r[2], m01i = r[3];
            float m10r = r[4], m10i = r[5], m11r = r[6], m11i = r[7];
            int bp = 11 - q;
            int lowmask = (1 << bp) - 1;
            #pragma unroll
            for (int k = 0; k < 8; ++k) {
                int p = tid + k * 256;
                int i0 = ((p & ~lowmask) << 1) | (p & lowmask);
                int i1 = i0 | (1 << bp);
                float2 a0 = st[i0], a1 = st[i1];
                float n0r = m00r * a0.x - m00i * a0.y + m01r * a1.x - m01i * a1.y;
                float n0i = m00r * a0.y + m00i * a0.x + m01r * a1.y + m01i * a1.x;
                float n1r = m10r * a0.x - m10i * a0.y + m11r * a1.x - m11i * a1.y;
                float n1i = m10r * a0.y + m10i * a0.x + m11r * a1.y + m11i * a1.x;
                st[i0] = make_float2(n0r, n0i);
                st[i1] = make_float2(n1r, n1i);
            }
            __syncthreads();
        }
        // CNOT chain q=0..10 == permutation new[j] = old[j ^ (j>>1)]
        float2 v[16];
        #pragma unroll
        for (int k = 0; k < 16; ++k) {
            int j = tid + k * 256;
            int gj = j ^ (j >> 1);
            v[k] = st[gj];
        }
        __syncthreads();
        #pragma unroll
        for (int k = 0; k < 16; ++k)
            st[tid + k * 256] = v[k];
        __syncthreads();
    }

    // ---- expectation values <Z_q> ----
    // j = tid + k*256: bits 7..0 = tid (qubits 4..11), bits 11..8 = k (qubits 0..3)
    float psum = 0.f;
    float zk0 = 0.f, zk1 = 0.f, zk2 = 0.f, zk3 = 0.f; // qubits 0..3 (k bits 3..0)
    #pragma unroll
    for (int k = 0; k < 16; ++k) {
        int j = tid + k * 256;
        float2 a = st[j];
        float p = a.x * a.x + a.y * a.y;
        psum += p;
        zk0 += (k & 8) ? -p : p;
        zk1 += (k & 4) ? -p : p;
        zk2 += (k & 2) ? -p : p;
        zk3 += (k & 1) ? -p : p;
    }
    float z[12];
    z[0] = zk0; z[1] = zk1; z[2] = zk2; z[3] = zk3;
    #pragma unroll
    for (int q = 4; q < 12; ++q)
        z[q] = ((tid >> (11 - q)) & 1) ? -psum : psum;

    // block reduction: wave shuffle then LDS
    int lane = tid & 63, wave = tid >> 6;
    #pragma unroll
    for (int q = 0; q < 12; ++q) {
        float v = z[q];
        #pragma unroll
        for (int off = 32; off > 0; off >>= 1)
            v += __shfl_down(v, off, 64);
        if (lane == 0) zred[wave][q] = v;
    }
    __syncthreads();
    if (tid < 12)
        zf[tid] = zred[0][tid] + zred[1][tid] + zred[2][tid] + zred[3][tid];
    __syncthreads();

    // fused linear: out[b][f] = bias[f] + sum_q zf[q] * W[f][q]
    if (tid < OUTF) {
        float acc = bias[tid];
        #pragma unroll
        for (int q = 0; q < 12; ++q)
            acc += zf[q] * W[tid * 12 + q];
        out[b * OUTF + tid] = acc;
    }
}

extern "C" void kernel_launch(void* const* d_in, const int* in_sizes, int n_in,
                              void* d_out, int out_size, void* d_ws, size_t ws_size,
                              hipStream_t stream) {
    const float* x      = (const float*)d_in[0];
    const float* params = (const float*)d_in[1];
    const float* W      = (const float*)d_in[2];
    const float* bias   = (const float*)d_in[3];
    float* out = (float*)d_out;
    float* rot = (float*)d_ws;   // 576 floats

    rot_precompute<<<1, 128, 0, stream>>>(params, rot);
    circuit_kernel<<<BATCH, 256, 0, stream>>>(x, rot, W, bias, out);
}

// Round 2
// 820.999 us; speedup vs baseline: 1.2435x; 1.2435x over previous
//
#include <hip/hip_runtime.h>

#define NQ 12
#define NL 6
#define NSTATES 4096
#define BATCH 8192
#define OUTF 64
#define NGROUPS 18

struct Group {
  unsigned short comb[16];  // XOR combos of the 4 gate masks
  unsigned short bk[8];     // complement basis vectors (thread bit k -> XOR bk[k])
  unsigned short f[4];      // side functionals per gate
  unsigned short coef[4];   // rot coefficient index (l*12+q)
};
struct Plan {
  Group g[NGROUPS];
  float zsign[12][16];      // measurement sign per (qubit, local amp)
  unsigned short fq[12];    // measurement functionals (base sign from j0)
};

__global__ void rot_precompute(const float* __restrict__ params, float* __restrict__ rot) {
  int gi = blockIdx.x * blockDim.x + threadIdx.x;
  if (gi >= NL * NQ) return;
  float phi = params[gi*3+0], theta = params[gi*3+1], omega = params[gi*3+2];
  float c = cosf(0.5f*theta), s = sinf(0.5f*theta);
  float apo = 0.5f*(phi+omega), amo = 0.5f*(phi-omega);
  float cpo = cosf(apo), spo = sinf(apo);
  float cmo = cosf(amo), smo = sinf(amo);
  float* r = rot + gi*8;
  // Rot = [[e^{-i(phi+omega)/2} c, -e^{i(phi-omega)/2} s],
  //        [e^{-i(phi-omega)/2} s,  e^{i(phi+omega)/2} c]]
  r[0]= cpo*c;  r[1]=-spo*c;
  r[2]=-cmo*s;  r[3]=-smo*s;
  r[4]= cmo*s;  r[5]=-smo*s;
  r[6]= cpo*c;  r[7]= spo*c;
}

__global__ __launch_bounds__(256) void circuit_kernel(
    const float* __restrict__ x, const float* __restrict__ rot,
    const float* __restrict__ W, const float* __restrict__ bias,
    float* __restrict__ out, Plan plan)
{
  __shared__ float2 st[NSTATES];
  const int b = blockIdx.x;
  const int tid = threadIdx.x;

  // ---- product-state init: data-encoding RY applied to |0...0> ----
  float cq[12], sq[12];  // indexed by bit position bp = 11-q
  #pragma unroll
  for (int q = 0; q < 12; ++q) {
    float sv, cv;
    sincosf(0.5f * x[b*12+q], &sv, &cv);
    cq[11-q] = cv; sq[11-q] = sv;
  }
  float lowp = 1.f;
  #pragma unroll
  for (int bp = 0; bp < 8; ++bp) lowp *= ((tid>>bp)&1) ? sq[bp] : cq[bp];
  #pragma unroll
  for (int k = 0; k < 16; ++k) {
    float hp = ((k&1)?sq[8]:cq[8]) * ((k&2)?sq[9]:cq[9]) *
               ((k&4)?sq[10]:cq[10]) * ((k&8)?sq[11]:cq[11]);
    st[tid + (k<<8)] = make_float2(lowp*hp, 0.f);
  }
  __syncthreads();

  float2 v[16];
  int j0 = 0;

  for (int grp = 0; grp < NGROUPS; ++grp) {
    const Group& G = plan.g[grp];
    j0 = 0;
    #pragma unroll
    for (int k = 0; k < 8; ++k) j0 ^= G.bk[k] & (-((tid>>k)&1));
    #pragma unroll
    for (int c = 0; c < 16; ++c) v[c] = st[j0 ^ G.comb[c]];
    #pragma unroll
    for (int i = 0; i < 4; ++i) {
      const float* rp = rot + G.coef[i]*8;
      float m00r=rp[0], m00i=rp[1], m01r=rp[2], m01i=rp[3];
      float m10r=rp[4], m10i=rp[5], m11r=rp[6], m11i=rp[7];
      bool s0 = __popc((unsigned)(j0 & G.f[i])) & 1;
      float A0r = s0?m11r:m00r, A0i = s0?m11i:m00i;
      float B0r = s0?m10r:m01r, B0i = s0?m10i:m01i;
      float A1r = s0?m00r:m11r, A1i = s0?m00i:m11i;
      float B1r = s0?m01r:m10r, B1i = s0?m01i:m10i;
      #pragma unroll
      for (int c = 0; c < 16; ++c) {
        if (c & (1<<i)) continue;
        int c1 = c | (1<<i);
        float2 a = v[c], bb = v[c1];
        v[c]  = make_float2(A0r*a.x - A0i*a.y + B0r*bb.x - B0i*bb.y,
                            A0r*a.y + A0i*a.x + B0r*bb.y + B0i*bb.x);
        v[c1] = make_float2(A1r*bb.x - A1i*bb.y + B1r*a.x - B1i*a.y,
                            A1r*bb.y + A1i*bb.x + B1r*a.y + B1i*a.x);
      }
    }
    if (grp == NGROUPS-1) break;   // keep final amps in registers
    #pragma unroll
    for (int c = 0; c < 16; ++c) st[j0 ^ G.comb[c]] = v[c];
    __syncthreads();
  }

  // ---- measurement: <Z_q> from registers ----
  float p[16];
  #pragma unroll
  for (int c = 0; c < 16; ++c) p[c] = v[c].x*v[c].x + v[c].y*v[c].y;
  float z[12];
  #pragma unroll
  for (int q = 0; q < 12; ++q) {
    float acc = 0.f;
    #pragma unroll
    for (int c = 0; c < 16; ++c) acc = fmaf(plan.zsign[q][c], p[c], acc);
    z[q] = (__popc((unsigned)(j0 & plan.fq[q])) & 1) ? -acc : acc;
  }

  __syncthreads();   // all st reads done; safe to reuse as reduction scratch
  float* red = (float*)st;
  int lane = tid & 63, wv = tid >> 6;
  #pragma unroll
  for (int q = 0; q < 12; ++q) {
    float val = z[q];
    #pragma unroll
    for (int off = 32; off; off >>= 1) val += __shfl_down(val, off, 64);
    if (lane == 0) red[wv*12 + q] = val;
  }
  __syncthreads();
  if (tid < 12) red[48 + tid] = red[tid] + red[12+tid] + red[24+tid] + red[36+tid];
  __syncthreads();
  if (tid < OUTF) {
    float acc = bias[tid];
    #pragma unroll
    for (int q = 0; q < 12; ++q) acc = fmaf(red[48+q], W[tid*12+q], acc);
    out[b*OUTF + tid] = acc;
  }
}

// ---------------- host-side plan construction (GF(2) linear algebra) --------

static void build_plan(Plan& P) {
  // g(j) = j ^ (j>>1): columns g(e_i)
  unsigned short gcol[12];
  for (int i = 0; i < 12; ++i) gcol[i] = (unsigned short)((1u<<i) | (i ? (1u<<(i-1)) : 0u));
  // sigma_l = g^l, columns
  unsigned short sig[7][12];
  for (int i = 0; i < 12; ++i) sig[0][i] = (unsigned short)(1u<<i);
  for (int l = 1; l < 7; ++l)
    for (int i = 0; i < 12; ++i) {
      unsigned vv = sig[l-1][i], r = 0;
      for (int t = 0; t < 12; ++t) if ((vv>>t)&1) r ^= gcol[t];
      sig[l][i] = (unsigned short)r;
    }
  // rows of sigma_l^{-1} via Gauss-Jordan on rows [M|I]
  unsigned short invrow[7][12];
  for (int l = 0; l < 7; ++l) {
    unsigned rowM[12], rowI[12];
    for (int r = 0; r < 12; ++r) {
      unsigned w = 0;
      for (int i = 0; i < 12; ++i) w |= ((sig[l][i]>>r)&1u)<<i;
      rowM[r] = w; rowI[r] = 1u<<r;
    }
    for (int c = 0; c < 12; ++c) {
      int piv = -1;
      for (int r = c; r < 12; ++r) if ((rowM[r]>>c)&1) { piv = r; break; }
      unsigned t = rowM[c]; rowM[c]=rowM[piv]; rowM[piv]=t;
      t = rowI[c]; rowI[c]=rowI[piv]; rowI[piv]=t;
      for (int r = 0; r < 12; ++r)
        if (r != c && ((rowM[r]>>c)&1)) { rowM[r]^=rowM[c]; rowI[r]^=rowI[c]; }
    }
    for (int r = 0; r < 12; ++r) invrow[l][r] = (unsigned short)rowI[r];
  }

  for (int l = 0; l < 6; ++l)
    for (int gi = 0; gi < 3; ++gi) {
      Group& G = P.g[l*3+gi];
      unsigned m[4];
      for (int i = 0; i < 4; ++i) {
        int q = gi*4 + i, bp = 11 - q;
        m[i] = sig[l][bp];
        G.f[i] = invrow[l][bp];
        G.coef[i] = (unsigned short)(l*12 + q);
      }
      for (int c = 0; c < 16; ++c) {
        unsigned cc = 0;
        for (int i = 0; i < 4; ++i) if ((c>>i)&1) cc ^= m[i];
        G.comb[c] = (unsigned short)cc;
      }
      // echelon pivots of span(m)
      unsigned red[4]; int piv[4];
      for (int i = 0; i < 4; ++i) {
        red[i] = m[i];
        for (int j = 0; j < i; ++j) if ((red[i]>>piv[j])&1) red[i] ^= red[j];
        piv[i] = 31 - __builtin_clz(red[i]);
      }
      bool isp[12] = {};
      for (int i = 0; i < 4; ++i) isp[piv[i]] = true;
      int dk[8], nk = 0;
      for (int d = 0; d < 12; ++d) if (!isp[d]) dk[nk++] = d;
      // complement basis; greedily XOR in span(m) elements so lane directions
      // (k=0..5) spread LDS bank bits 0..3 (avoids 32-way ds_read_b64 conflicts)
      unsigned bas[4] = {0,0,0,0};
      auto reduce4 = [&](unsigned vv)->unsigned {
        vv &= 0xF;
        for (int bit = 3; bit >= 0; --bit)
          if (((vv>>bit)&1) && bas[bit]) vv ^= bas[bit];
        return vv;
      };
      for (int k = 0; k < 8; ++k) {
        unsigned base = 1u << dk[k];
        unsigned chosen = base;
        unsigned r4 = reduce4(base);
        if (!r4) {
          for (int c = 1; c < 16; ++c) {
            unsigned cand = base ^ G.comb[c];
            unsigned rr = reduce4(cand);
            if (rr) { chosen = cand; r4 = rr; break; }
          }
        }
        if (r4) { int tb = 31 - __builtin_clz(r4); bas[tb] = r4; }
        G.bk[k] = (unsigned short)chosen;
      }
    }

  // measurement: sigma_final = g^6
  for (int q = 0; q < 12; ++q) {
    unsigned short fq = invrow[6][11-q];
    P.fq[q] = fq;
    for (int c = 0; c < 16; ++c)
      P.zsign[q][c] =
        (__builtin_popcount((unsigned)(P.g[NGROUPS-1].comb[c] & fq)) & 1) ? -1.f : 1.f;
  }
}

extern "C" void kernel_launch(void* const* d_in, const int* in_sizes, int n_in,
                              void* d_out, int out_size, void* d_ws, size_t ws_size,
                              hipStream_t stream) {
  const float* x      = (const float*)d_in[0];
  const float* params = (const float*)d_in[1];
  const float* W      = (const float*)d_in[2];
  const float* bias   = (const float*)d_in[3];
  float* out = (float*)d_out;
  float* rot = (float*)d_ws;   // 576 floats

  Plan P;
  build_plan(P);

  rot_precompute<<<1, 128, 0, stream>>>(params, rot);
  circuit_kernel<<<BATCH, 256, 0, stream>>>(x, rot, W, bias, out, P);
}

// Round 4
// 362.063 us; speedup vs baseline: 2.8196x; 2.2676x over previous
//
#include <hip/hip_runtime.h>
#include <math.h>

typedef _Float16 h8 __attribute__((ext_vector_type(8)));
typedef float f4 __attribute__((ext_vector_type(4)));
typedef unsigned int u32;

#define BATCH 8192

// Swizzle on amp index (float2 units): XOR bits 3:1 with hash of upper bits.
// Preserves 16B alignment of amp-pairs; spreads every access pattern to the
// minimal 8 lanes per LDS bank-group.
#define SWZA(i) ((i) ^ (((((i) >> 4) ^ ((i) >> 7) ^ ((i) >> 10)) & 7) << 1))

// ---------------------------------------------------------------------------
// Stage matrices as MFMA B-operands, split precision.
// Per stage (layer 0..5 x axis {L,M,H}) 4 real 16(n) x 32(k) f16 mats:
//   re_hi, re_lo(*2^11), im_hi, im_lo(*2^11);  k = 2*slot + ri.
//   B_re[2a][n]=Re M[n][l(a)], B_re[2a+1][n]=-Im M[n][l(a)]
//   B_im[2a][n]=Im M[n][l(a)], B_im[2a+1][n]= Re M[n][l(a)]
// Fold-L stages (axis 0, layer>0): slot order Gray-permuted (CNOT fold).
// ---------------------------------------------------------------------------
__global__ void build_mats(const float* __restrict__ params, _Float16* __restrict__ ws) {
  int s = blockIdx.x, layer = s / 3, axis = s % 3;
  int t = threadIdx.x, n = t >> 4, col = t & 15;
  double Er = 1.0, Ei = 0.0;
  #pragma unroll
  for (int j = 0; j < 4; ++j) {
    int q = (axis == 0) ? (11 - j) : (axis == 1) ? (7 - j) : (3 - j);
    const float* pp = params + (layer * 12 + q) * 3;
    double phi = pp[0], th = pp[1], om = pp[2];
    double c = cos(0.5 * th), sn = sin(0.5 * th);
    double aa = 0.5 * (phi + om), bb = 0.5 * (phi - om);
    int nb = (n >> j) & 1, cb = (col >> j) & 1;
    double mr, mi;
    if (!nb) {
      if (!cb) { mr =  cos(aa) * c;  mi = -sin(aa) * c; }
      else     { mr = -cos(bb) * sn; mi = -sin(bb) * sn; }
    } else {
      if (!cb) { mr =  cos(bb) * sn; mi = -sin(bb) * sn; }
      else     { mr =  cos(aa) * c;  mi =  sin(aa) * c; }
    }
    double nr = Er * mr - Ei * mi, ni = Er * mi + Ei * mr;
    Er = nr; Ei = ni;
  }
  int a_;
  if (axis == 0 && layer > 0) {
    int kb = col >> 2, ll = col & 3;
    a_ = kb * 4 + ((ll ^ (ll >> 1)) ^ ((kb & 1) << 1));
  } else a_ = col;
  _Float16* reh = ws + s * 2048;
  _Float16* rel = reh + 512;
  _Float16* imh = reh + 1024;
  _Float16* iml = reh + 1536;
  int o0 = n * 32 + 2 * a_, o1 = o0 + 1;
  float v;
  _Float16 h;
  v = (float)Er;  h = (_Float16)v; reh[o0] = h; rel[o0] = (_Float16)((v - (float)h) * 2048.f);
  v = (float)-Ei; h = (_Float16)v; reh[o1] = h; rel[o1] = (_Float16)((v - (float)h) * 2048.f);
  v = (float)Ei;  h = (_Float16)v; imh[o0] = h; iml[o0] = (_Float16)((v - (float)h) * 2048.f);
  v = (float)Er;  h = (_Float16)v; imh[o1] = h; iml[o1] = (_Float16)((v - (float)h) * 2048.f);
}

// ---------------------------------------------------------------------------
// One sample per 256-thread block. State: 4096 float2 amps in LDS (32 KB).
// Layout cycles [h][m][l] -L-> [l][h][m] -M-> [m][l][h] -H-> [h][m][l].
// CNOT perms folded into next-layer L reads + matrix slot order + meas signs.
// ---------------------------------------------------------------------------
__global__ __launch_bounds__(256) void circuit_kernel(
    const float* __restrict__ x, const _Float16* __restrict__ mats,
    const float* __restrict__ W, const float* __restrict__ bias,
    float* __restrict__ out) {
  __shared__ __align__(16) float2 st[4096];
  __shared__ float red[64];

  const int b = blockIdx.x;
  const int tid = threadIdx.x;
  const int lane = tid & 63, w = tid >> 6;
  const int r = lane & 15, kb = lane >> 4;

  // ---- init: product state of the data-encoding RY layer ----
  float cs[12], sn_[12];  // indexed by global bit i (qubit q <-> bit 11-q)
  #pragma unroll
  for (int q = 0; q < 12; ++q) {
    float sv, cv;
    sincosf(0.5f * x[b * 12 + q], &sv, &cv);
    cs[11 - q] = cv; sn_[11 - q] = sv;
  }
  {
    int hb = (w << 6) | lane;  // amp >> 4
    float basep = 1.f;
    #pragma unroll
    for (int i = 0; i < 8; ++i) basep *= ((hb >> i) & 1) ? sn_[4 + i] : cs[4 + i];
    float p2[4], q2[4];
    #pragma unroll
    for (int v = 0; v < 4; ++v) {
      p2[v] = ((v & 1) ? sn_[0] : cs[0]) * ((v & 2) ? sn_[1] : cs[1]);
      q2[v] = ((v & 1) ? sn_[2] : cs[2]) * ((v & 2) ? sn_[3] : cs[3]) * basep;
    }
    #pragma unroll
    for (int g = 0; g < 4; ++g) {
      int idx = w * 1024 + lane * 16 + g * 4;
      float a0 = q2[g] * p2[0], a1 = q2[g] * p2[1];
      float a2 = q2[g] * p2[2], a3 = q2[g] * p2[3];
      *(float4*)&st[SWZA(idx)]     = make_float4(a0, 0.f, a1, 0.f);
      *(float4*)&st[SWZA(idx + 2)] = make_float4(a2, 0.f, a3, 0.f);
    }
  }
  __syncthreads();

  // fold-read constants
  const int g4r = r ^ (r >> 1);
  const int kb0 = kb & 1, kb1 = kb >> 1, m0 = r & 1;
  const int ob = ((kb1 ^ m0) << 1) | (kb0 ^ kb1);

  for (int layer = 0; layer < 6; ++layer) {
    #pragma unroll
    for (int axis = 0; axis < 3; ++axis) {
      const _Float16* mb = mats + (layer * 3 + axis) * 2048;
      const int bo = r * 32 + kb * 8;
      h8 breh = *(const h8*)(mb + bo);
      h8 brel = *(const h8*)(mb + 512 + bo);
      h8 bimh = *(const h8*)(mb + 1024 + bo);
      h8 biml = *(const h8*)(mb + 1536 + bo);
      float4 pA[4], pB[4];
      const bool fold = (axis == 0) && (layer > 0);
      #pragma unroll
      for (int i = 0; i < 4; ++i) {
        int tile = w * 4 + i;
        int ridx;
        if (fold) {
          int oh = tile ^ (tile >> 1);
          int om = g4r ^ ((tile & 1) << 3);
          ridx = (oh << 8) | (om << 4) | (ob << 2);
        } else {
          ridx = (tile << 8) | (r << 4) | (kb << 2);
        }
        float4 ra = *(const float4*)&st[SWZA(ridx)];
        float4 rb = *(const float4*)&st[SWZA(ridx + 2)];
        float fv[8] = {ra.x, ra.y, ra.z, ra.w, rb.x, rb.y, rb.z, rb.w};
        h8 ahi, alo;
        #pragma unroll
        for (int j = 0; j < 8; ++j) {
          _Float16 h = (_Float16)fv[j];
          ahi[j] = h;
          alo[j] = (_Float16)((fv[j] - (float)h) * 2048.f);
        }
        f4 mr = {0.f, 0.f, 0.f, 0.f}, mi = {0.f, 0.f, 0.f, 0.f};
        f4 cr = {0.f, 0.f, 0.f, 0.f}, ci = {0.f, 0.f, 0.f, 0.f};
        mr = __builtin_amdgcn_mfma_f32_16x16x32_f16(ahi, breh, mr, 0, 0, 0);
        cr = __builtin_amdgcn_mfma_f32_16x16x32_f16(alo, breh, cr, 0, 0, 0);
        cr = __builtin_amdgcn_mfma_f32_16x16x32_f16(ahi, brel, cr, 0, 0, 0);
        mi = __builtin_amdgcn_mfma_f32_16x16x32_f16(ahi, bimh, mi, 0, 0, 0);
        ci = __builtin_amdgcn_mfma_f32_16x16x32_f16(alo, bimh, ci, 0, 0, 0);
        ci = __builtin_amdgcn_mfma_f32_16x16x32_f16(ahi, biml, ci, 0, 0, 0);
        const float sc = 1.f / 2048.f;
        pA[i] = make_float4(fmaf(cr[0], sc, mr[0]), fmaf(ci[0], sc, mi[0]),
                            fmaf(cr[1], sc, mr[1]), fmaf(ci[1], sc, mi[1]));
        pB[i] = make_float4(fmaf(cr[2], sc, mr[2]), fmaf(ci[2], sc, mi[2]),
                            fmaf(cr[3], sc, mr[3]), fmaf(ci[3], sc, mi[3]));
      }
      __syncthreads();  // all reads of this stage complete
      #pragma unroll
      for (int i = 0; i < 4; ++i) {
        int tile = w * 4 + i;
        int widx = (r << 8) | (tile << 4) | (kb << 2);
        *(float4*)&st[SWZA(widx)]     = pA[i];
        *(float4*)&st[SWZA(widx + 2)] = pB[i];
      }
      __syncthreads();
    }
  }

  // ---- measurement: final CNOT folded via parity signs ----
  float psum = 0.f, A0 = 0.f, A1 = 0.f, A2 = 0.f, A3 = 0.f;
  #pragma unroll
  for (int g = 0; g < 4; ++g) {
    int idx = w * 1024 + lane * 16 + g * 4;
    float4 ra = *(const float4*)&st[SWZA(idx)];
    float4 rb = *(const float4*)&st[SWZA(idx + 2)];
    float re_[4] = {ra.x, ra.z, rb.x, rb.z};
    float im_[4] = {ra.y, ra.w, rb.y, rb.w};
    #pragma unroll
    for (int j = 0; j < 4; ++j) {
      int tt = g * 4 + j;  // compile-time -> signs fold to add/sub
      float p = re_[j] * re_[j] + im_[j] * im_[j];
      psum += p;
      A0 += (__builtin_popcount((unsigned)tt) & 1) ? -p : p;
      A1 += (__builtin_popcount((unsigned)(tt >> 1)) & 1) ? -p : p;
      A2 += (__builtin_popcount((unsigned)(tt >> 2)) & 1) ? -p : p;
      A3 += (__builtin_popcount((unsigned)(tt >> 3)) & 1) ? -p : p;
    }
  }
  float zs[12];
  {
    int u = (w << 6) | lane;  // amp >> 4
    int pu = __builtin_popcount((unsigned)u) & 1;
    zs[11] = pu ? -A0 : A0;
    zs[10] = pu ? -A1 : A1;
    zs[9]  = pu ? -A2 : A2;
    zs[8]  = pu ? -A3 : A3;
    #pragma unroll
    for (int q = 0; q <= 7; ++q) {
      int sgn = __builtin_popcount((unsigned)(u >> (7 - q))) & 1;
      zs[q] = sgn ? -psum : psum;
    }
  }
  #pragma unroll
  for (int q = 0; q < 12; ++q) {
    float v = zs[q];
    #pragma unroll
    for (int off = 1; off < 64; off <<= 1) v += __shfl_xor(v, off, 64);
    zs[q] = v;
  }
  if (lane == 0) {
    #pragma unroll
    for (int q = 0; q < 12; ++q) red[w * 12 + q] = zs[q];
  }
  __syncthreads();
  if (tid < 12) red[48 + tid] = red[tid] + red[12 + tid] + red[24 + tid] + red[36 + tid];
  __syncthreads();
  if (tid < 64) {
    float acc = bias[tid];
    #pragma unroll
    for (int q = 0; q < 12; ++q) acc = fmaf(red[48 + q], W[tid * 12 + q], acc);
    out[b * 64 + tid] = acc;
  }
}

extern "C" void kernel_launch(void* const* d_in, const int* in_sizes, int n_in,
                              void* d_out, int out_size, void* d_ws, size_t ws_size,
                              hipStream_t stream) {
  const float* x      = (const float*)d_in[0];
  const float* params = (const float*)d_in[1];
  const float* W      = (const float*)d_in[2];
  const float* bias   = (const float*)d_in[3];
  float* out = (float*)d_out;
  _Float16* mats = (_Float16*)d_ws;  // 18 * 2048 f16 = 73728 bytes

  build_mats<<<18, 256, 0, stream>>>(params, mats);
  circuit_kernel<<<BATCH, 256, 0, stream>>>(x, mats, W, bias, out);
}

// Round 6
// 332.932 us; speedup vs baseline: 3.0663x; 1.0875x over previous
//
#include <hip/hip_runtime.h>
#include <math.h>

typedef _Float16 h8 __attribute__((ext_vector_type(8)));
typedef float f4 __attribute__((ext_vector_type(4)));

#define BATCH 8192

// Swizzle on amp index (float2 units): XOR bits 3:1 with hash of upper bits.
// (round-4 verbatim; validated)
#define SWZA(i) ((i) ^ (((((i) >> 4) ^ ((i) >> 7) ^ ((i) >> 10)) & 7) << 1))

// ---------------------------------------------------------------------------
// Stage matrices as MFMA B-operands, split precision (hi + lo*2^11 f16).
// (round-4 verbatim, double trig)
// ---------------------------------------------------------------------------
__global__ void build_mats(const float* __restrict__ params, _Float16* __restrict__ ws) {
  int s = blockIdx.x, layer = s / 3, axis = s % 3;
  int t = threadIdx.x, n = t >> 4, col = t & 15;
  double Er = 1.0, Ei = 0.0;
  #pragma unroll
  for (int j = 0; j < 4; ++j) {
    int q = (axis == 0) ? (11 - j) : (axis == 1) ? (7 - j) : (3 - j);
    const float* pp = params + (layer * 12 + q) * 3;
    double phi = pp[0], th = pp[1], om = pp[2];
    double c = cos(0.5 * th), sn = sin(0.5 * th);
    double aa = 0.5 * (phi + om), bb = 0.5 * (phi - om);
    int nb = (n >> j) & 1, cb = (col >> j) & 1;
    double mr, mi;
    if (!nb) {
      if (!cb) { mr =  cos(aa) * c;  mi = -sin(aa) * c; }
      else     { mr = -cos(bb) * sn; mi = -sin(bb) * sn; }
    } else {
      if (!cb) { mr =  cos(bb) * sn; mi = -sin(bb) * sn; }
      else     { mr =  cos(aa) * c;  mi =  sin(aa) * c; }
    }
    double nr = Er * mr - Ei * mi, ni = Er * mi + Ei * mr;
    Er = nr; Ei = ni;
  }
  int a_;
  if (axis == 0 && layer > 0) {
    int kb = col >> 2, ll = col & 3;
    a_ = kb * 4 + ((ll ^ (ll >> 1)) ^ ((kb & 1) << 1));
  } else a_ = col;
  _Float16* reh = ws + s * 2048;
  _Float16* rel = reh + 512;
  _Float16* imh = reh + 1024;
  _Float16* iml = reh + 1536;
  int o0 = n * 32 + 2 * a_, o1 = o0 + 1;
  float v;
  _Float16 h;
  v = (float)Er;  h = (_Float16)v; reh[o0] = h; rel[o0] = (_Float16)((v - (float)h) * 2048.f);
  v = (float)-Ei; h = (_Float16)v; reh[o1] = h; rel[o1] = (_Float16)((v - (float)h) * 2048.f);
  v = (float)Ei;  h = (_Float16)v; imh[o0] = h; iml[o0] = (_Float16)((v - (float)h) * 2048.f);
  v = (float)Er;  h = (_Float16)v; imh[o1] = h; iml[o1] = (_Float16)((v - (float)h) * 2048.f);
}

// ---------------------------------------------------------------------------
// Round-4 kernel with ONE change: L and M stages fused in registers
// (L's D-frag (m=4kb+j, l'=r) IS M's A-frag), M output scatter-written.
// Per layer: 2 LDS round trips instead of 3, 4 barriers instead of 6.
// ---------------------------------------------------------------------------
__global__ __launch_bounds__(256, 4) void circuit_kernel(
    const float* __restrict__ x, const _Float16* __restrict__ mats,
    const float* __restrict__ W, const float* __restrict__ bias,
    float* __restrict__ out) {
  __shared__ __align__(16) float2 st[4096];
  __shared__ float red[64];

  const int b = blockIdx.x;
  const int tid = threadIdx.x;
  const int lane = tid & 63, w = tid >> 6;
  const int r = lane & 15, kb = lane >> 4;

  // ---- init (round-4 verbatim) ----
  float cs[12], sn_[12];
  #pragma unroll
  for (int q = 0; q < 12; ++q) {
    float sv, cv;
    sincosf(0.5f * x[b * 12 + q], &sv, &cv);
    cs[11 - q] = cv; sn_[11 - q] = sv;
  }
  {
    int hb = (w << 6) | lane;
    float basep = 1.f;
    #pragma unroll
    for (int i = 0; i < 8; ++i) basep *= ((hb >> i) & 1) ? sn_[4 + i] : cs[4 + i];
    float p2[4], q2[4];
    #pragma unroll
    for (int v = 0; v < 4; ++v) {
      p2[v] = ((v & 1) ? sn_[0] : cs[0]) * ((v & 2) ? sn_[1] : cs[1]);
      q2[v] = ((v & 1) ? sn_[2] : cs[2]) * ((v & 2) ? sn_[3] : cs[3]) * basep;
    }
    #pragma unroll
    for (int g = 0; g < 4; ++g) {
      int idx = w * 1024 + lane * 16 + g * 4;
      float a0 = q2[g] * p2[0], a1 = q2[g] * p2[1];
      float a2 = q2[g] * p2[2], a3 = q2[g] * p2[3];
      *(float4*)&st[SWZA(idx)]     = make_float4(a0, 0.f, a1, 0.f);
      *(float4*)&st[SWZA(idx + 2)] = make_float4(a2, 0.f, a3, 0.f);
    }
  }
  __syncthreads();

  // fold-read constants (round-4 verbatim)
  const int g4r = r ^ (r >> 1);
  const int kb0 = kb & 1, kb1 = kb >> 1, m0 = r & 1;
  const int ob = ((kb1 ^ m0) << 1) | (kb0 ^ kb1);
  const int bo = r * 32 + kb * 8;
  const float sc = 1.f / 2048.f;

  for (int layer = 0; layer < 6; ++layer) {
    // ======== phase 1: L-stage (fold read) fused with M-stage ========
    const _Float16* mbL = mats + (layer * 3 + 0) * 2048;
    const _Float16* mbM = mats + (layer * 3 + 1) * 2048;
    h8 LbRh = *(const h8*)(mbL + bo),        LbRl = *(const h8*)(mbL + 512 + bo);
    h8 LbIh = *(const h8*)(mbL + 1024 + bo), LbIl = *(const h8*)(mbL + 1536 + bo);
    h8 MbRh = *(const h8*)(mbM + bo),        MbRl = *(const h8*)(mbM + 512 + bo);
    h8 MbIh = *(const h8*)(mbM + 1024 + bo), MbIl = *(const h8*)(mbM + 1536 + bo);
    float2 pend[4][4];
    const bool fold = (layer > 0);
    #pragma unroll
    for (int i = 0; i < 4; ++i) {
      int tile = w * 4 + i;
      int ridx;
      if (fold) {
        int oh = tile ^ (tile >> 1);
        int om = g4r ^ ((tile & 1) << 3);
        ridx = (oh << 8) | (om << 4) | (ob << 2);
      } else {
        ridx = (tile << 8) | (r << 4) | (kb << 2);
      }
      float4 ra = *(const float4*)&st[SWZA(ridx)];
      float4 rb = *(const float4*)&st[SWZA(ridx + 2)];
      float fv[8] = {ra.x, ra.y, ra.z, ra.w, rb.x, rb.y, rb.z, rb.w};
      h8 ahi, alo;
      #pragma unroll
      for (int j = 0; j < 8; ++j) {
        _Float16 h = (_Float16)fv[j];
        ahi[j] = h;
        alo[j] = (_Float16)((fv[j] - (float)h) * 2048.f);
      }
      f4 mr = {0.f,0.f,0.f,0.f}, mi = {0.f,0.f,0.f,0.f};
      f4 cr = {0.f,0.f,0.f,0.f}, ci = {0.f,0.f,0.f,0.f};
      mr = __builtin_amdgcn_mfma_f32_16x16x32_f16(ahi, LbRh, mr, 0, 0, 0);
      cr = __builtin_amdgcn_mfma_f32_16x16x32_f16(alo, LbRh, cr, 0, 0, 0);
      cr = __builtin_amdgcn_mfma_f32_16x16x32_f16(ahi, LbRl, cr, 0, 0, 0);
      mi = __builtin_amdgcn_mfma_f32_16x16x32_f16(ahi, LbIh, mi, 0, 0, 0);
      ci = __builtin_amdgcn_mfma_f32_16x16x32_f16(alo, LbIh, ci, 0, 0, 0);
      ci = __builtin_amdgcn_mfma_f32_16x16x32_f16(ahi, LbIl, ci, 0, 0, 0);
      // combine L output (same values round 4 wrote to LDS), re-split for M
      h8 bhi, blo;
      #pragma unroll
      for (int j = 0; j < 4; ++j) {
        float gr = fmaf(cr[j], sc, mr[j]);
        float gi = fmaf(ci[j], sc, mi[j]);
        _Float16 hr = (_Float16)gr, hm = (_Float16)gi;
        bhi[2*j] = hr; bhi[2*j+1] = hm;
        blo[2*j]   = (_Float16)((gr - (float)hr) * 2048.f);
        blo[2*j+1] = (_Float16)((gi - (float)hm) * 2048.f);
      }
      f4 nr = {0.f,0.f,0.f,0.f}, ni = {0.f,0.f,0.f,0.f};
      f4 dr = {0.f,0.f,0.f,0.f}, di = {0.f,0.f,0.f,0.f};
      nr = __builtin_amdgcn_mfma_f32_16x16x32_f16(bhi, MbRh, nr, 0, 0, 0);
      dr = __builtin_amdgcn_mfma_f32_16x16x32_f16(blo, MbRh, dr, 0, 0, 0);
      dr = __builtin_amdgcn_mfma_f32_16x16x32_f16(bhi, MbRl, dr, 0, 0, 0);
      ni = __builtin_amdgcn_mfma_f32_16x16x32_f16(bhi, MbIh, ni, 0, 0, 0);
      di = __builtin_amdgcn_mfma_f32_16x16x32_f16(blo, MbIh, di, 0, 0, 0);
      di = __builtin_amdgcn_mfma_f32_16x16x32_f16(bhi, MbIl, di, 0, 0, 0);
      #pragma unroll
      for (int j = 0; j < 4; ++j)
        pend[i][j] = make_float2(fmaf(dr[j], sc, nr[j]), fmaf(di[j], sc, ni[j]));
    }
    __syncthreads();  // all S_in reads complete
    // scatter-write S_mid [m'][l'][h]: amp = (r<<8)|((4kb+j)<<4)|tile
    #pragma unroll
    for (int i = 0; i < 4; ++i) {
      int tile = w * 4 + i;
      #pragma unroll
      for (int j = 0; j < 4; ++j) {
        int amp = (r << 8) | ((4 * kb + j) << 4) | tile;
        st[SWZA(amp)] = pend[i][j];
      }
    }
    __syncthreads();  // S_mid complete

    // ======== phase 2: H stage (round-4 axis=2 verbatim) ========
    const _Float16* mbH = mats + (layer * 3 + 2) * 2048;
    h8 HbRh = *(const h8*)(mbH + bo),        HbRl = *(const h8*)(mbH + 512 + bo);
    h8 HbIh = *(const h8*)(mbH + 1024 + bo), HbIl = *(const h8*)(mbH + 1536 + bo);
    float4 pA[4], pB[4];
    #pragma unroll
    for (int i = 0; i < 4; ++i) {
      int tile = w * 4 + i;
      int ridx = (tile << 8) | (r << 4) | (kb << 2);
      float4 ra = *(const float4*)&st[SWZA(ridx)];
      float4 rb = *(const float4*)&st[SWZA(ridx + 2)];
      float fv[8] = {ra.x, ra.y, ra.z, ra.w, rb.x, rb.y, rb.z, rb.w};
      h8 ahi, alo;
      #pragma unroll
      for (int j = 0; j < 8; ++j) {
        _Float16 h = (_Float16)fv[j];
        ahi[j] = h;
        alo[j] = (_Float16)((fv[j] - (float)h) * 2048.f);
      }
      f4 mr = {0.f,0.f,0.f,0.f}, mi = {0.f,0.f,0.f,0.f};
      f4 cr = {0.f,0.f,0.f,0.f}, ci = {0.f,0.f,0.f,0.f};
      mr = __builtin_amdgcn_mfma_f32_16x16x32_f16(ahi, HbRh, mr, 0, 0, 0);
      cr = __builtin_amdgcn_mfma_f32_16x16x32_f16(alo, HbRh, cr, 0, 0, 0);
      cr = __builtin_amdgcn_mfma_f32_16x16x32_f16(ahi, HbRl, cr, 0, 0, 0);
      mi = __builtin_amdgcn_mfma_f32_16x16x32_f16(ahi, HbIh, mi, 0, 0, 0);
      ci = __builtin_amdgcn_mfma_f32_16x16x32_f16(alo, HbIh, ci, 0, 0, 0);
      ci = __builtin_amdgcn_mfma_f32_16x16x32_f16(ahi, HbIl, ci, 0, 0, 0);
      pA[i] = make_float4(fmaf(cr[0], sc, mr[0]), fmaf(ci[0], sc, mi[0]),
                          fmaf(cr[1], sc, mr[1]), fmaf(ci[1], sc, mi[1]));
      pB[i] = make_float4(fmaf(cr[2], sc, mr[2]), fmaf(ci[2], sc, mi[2]),
                          fmaf(cr[3], sc, mr[3]), fmaf(ci[3], sc, mi[3]));
    }
    __syncthreads();  // all S_mid reads complete
    #pragma unroll
    for (int i = 0; i < 4; ++i) {
      int tile = w * 4 + i;
      int widx = (r << 8) | (tile << 4) | (kb << 2);
      *(float4*)&st[SWZA(widx)]     = pA[i];
      *(float4*)&st[SWZA(widx + 2)] = pB[i];
    }
    __syncthreads();  // S_out complete
  }

  // ---- measurement (round-4 verbatim) ----
  float psum = 0.f, A0 = 0.f, A1 = 0.f, A2 = 0.f, A3 = 0.f;
  #pragma unroll
  for (int g = 0; g < 4; ++g) {
    int idx = w * 1024 + lane * 16 + g * 4;
    float4 ra = *(const float4*)&st[SWZA(idx)];
    float4 rb = *(const float4*)&st[SWZA(idx + 2)];
    float re_[4] = {ra.x, ra.z, rb.x, rb.z};
    float im_[4] = {ra.y, ra.w, rb.y, rb.w};
    #pragma unroll
    for (int j = 0; j < 4; ++j) {
      int tt = g * 4 + j;
      float p = re_[j] * re_[j] + im_[j] * im_[j];
      psum += p;
      A0 += (__builtin_popcount((unsigned)tt) & 1) ? -p : p;
      A1 += (__builtin_popcount((unsigned)(tt >> 1)) & 1) ? -p : p;
      A2 += (__builtin_popcount((unsigned)(tt >> 2)) & 1) ? -p : p;
      A3 += (__builtin_popcount((unsigned)(tt >> 3)) & 1) ? -p : p;
    }
  }
  float zs[12];
  {
    int u = (w << 6) | lane;
    int pu = __builtin_popcount((unsigned)u) & 1;
    zs[11] = pu ? -A0 : A0;
    zs[10] = pu ? -A1 : A1;
    zs[9]  = pu ? -A2 : A2;
    zs[8]  = pu ? -A3 : A3;
    #pragma unroll
    for (int q = 0; q <= 7; ++q) {
      int sgn = __builtin_popcount((unsigned)(u >> (7 - q))) & 1;
      zs[q] = sgn ? -psum : psum;
    }
  }
  #pragma unroll
  for (int q = 0; q < 12; ++q) {
    float v = zs[q];
    #pragma unroll
    for (int off = 1; off < 64; off <<= 1) v += __shfl_xor(v, off, 64);
    zs[q] = v;
  }
  if (lane == 0) {
    #pragma unroll
    for (int q = 0; q < 12; ++q) red[w * 12 + q] = zs[q];
  }
  __syncthreads();
  if (tid < 12) red[48 + tid] = red[tid] + red[12 + tid] + red[24 + tid] + red[36 + tid];
  __syncthreads();
  if (tid < 64) {
    float acc = bias[tid];
    #pragma unroll
    for (int q = 0; q < 12; ++q) acc = fmaf(red[48 + q], W[tid * 12 + q], acc);
    out[b * 64 + tid] = acc;
  }
}

extern "C" void kernel_launch(void* const* d_in, const int* in_sizes, int n_in,
                              void* d_out, int out_size, void* d_ws, size_t ws_size,
                              hipStream_t stream) {
  const float* x      = (const float*)d_in[0];
  const float* params = (const float*)d_in[1];
  const float* W      = (const float*)d_in[2];
  const float* bias   = (const float*)d_in[3];
  float* out = (float*)d_out;
  _Float16* mats = (_Float16*)d_ws;  // 18 * 2048 f16 = 73728 bytes

  build_mats<<<18, 256, 0, stream>>>(params, mats);
  circuit_kernel<<<BATCH, 256, 0, stream>>>(x, mats, W, bias, out);
}